// Round 5
// baseline (515.939 us; speedup 1.0000x reference)
//
#include <hip/hip_runtime.h>
#include <math.h>

// ---------------- problem constants ----------------
#define LAYERS 2
#define DMODEL 256
#define NHEAD  8
#define DHEAD  32
#define FF     512
#define KNB    9
#define MB     4
#define G1D    40
#define G2D    40
#define NTGT   2048
#define NCTX   1600          // G1D*G2D
#define RC     (MB*NCTX)     // 6400 grid rows
#define RT     (MB*NTGT)     // 8192 target rows

typedef __attribute__((ext_vector_type(8))) short short8;   // 8 bf16 (4 VGPRs)
typedef __attribute__((ext_vector_type(4))) float f32x4;    // mfma C/D

#if __has_builtin(__builtin_amdgcn_exp2f)
#define EXP2(x) __builtin_amdgcn_exp2f(x)
#else
#define EXP2(x) exp2f(x)
#endif

// ---------------- workspace layout (float offsets) ----------------
#define ZC_OFF    0
#define H_OFF     1638400
#define QKV_OFF   (H_OFF + 2097152)
#define Q_OFF     (QKV_OFF + 4915200)
#define O_OFF     (Q_OFF + 2097152)
#define IDX_OFF   (O_OFF + 2097152)
#define MASK_OFF  (IDX_OFF + 73728)
#define WS_FLOATS (MASK_OFF + 73728)

static __device__ __forceinline__ float gelu_f(float x){
  float t = tanhf(0.7978845608028654f * (x + 0.044715f * x * x * x));
  return 0.5f * x * (1.0f + t);
}

static __device__ __forceinline__ unsigned int bf16_rne(float x){
  unsigned int u = __float_as_uint(x);
  return (u + 0x7fffu + ((u >> 16) & 1u)) >> 16;
}
static __device__ __forceinline__ unsigned int pack_bf16x2(float lo, float hi){
  return bf16_rne(lo) | (bf16_rne(hi) << 16);
}
// truncating pack (hot path only: P values in [0,1])
static __device__ __forceinline__ unsigned int pack_bf16x2_trunc(float lo, float hi){
  return (__float_as_uint(lo) >> 16) | (__float_as_uint(hi) & 0xffff0000u);
}

// ---------------- utility: vectorized copy ----------------
__global__ void copy_kernel(const float* __restrict__ src, float* __restrict__ dst, int n4){
  int i = blockIdx.x * blockDim.x + threadIdx.x;
  if (i < n4) ((float4*)dst)[i] = ((const float4*)src)[i];
}

// ---------------- nearest-grid-neighbour index/mask precompute ----------------
__global__ void nn_idx_kernel(const float* __restrict__ xc, const float* __restrict__ xt,
                              int* __restrict__ idx, float* __restrict__ mask){
  int g = blockIdx.x * blockDim.x + threadIdx.x;
  if (g >= MB * NTGT) return;
  int m = g >> 11;
  float x0 = xt[(size_t)g * 2 + 0];
  float x1 = xt[(size_t)g * 2 + 1];
  const float* xcm = xc + (size_t)m * G1D * G2D * 2;
  int n0 = 0; float b0 = 1e30f;
  for (int i = 0; i < G1D; i++){
    float d = fabsf(x0 - xcm[i * (G2D * 2)]);
    if (d < b0){ b0 = d; n0 = i; }
  }
  int n1 = 0; float b1 = 1e30f;
  for (int j = 0; j < G2D; j++){
    float d = fabsf(x1 - xcm[j * 2 + 1]);
    if (d < b1){ b1 = d; n1 = j; }
  }
  #pragma unroll
  for (int a = 0; a < 3; a++){
    int r0 = n0 + a - 1;
    bool v0 = (r0 >= 0) && (r0 < G1D);
    int i0 = min(max(r0, 0), G1D - 1);
    #pragma unroll
    for (int b = 0; b < 3; b++){
      int r1 = n1 + b - 1;
      bool v1 = (r1 >= 0) && (r1 < G2D);
      int i1 = min(max(r1, 0), G2D - 1);
      idx [(size_t)g * KNB + a * 3 + b] = i0 * G2D + i1;
      mask[(size_t)g * KNB + a * 3 + b] = (v0 && v1) ? 1.0f : 0.0f;
    }
  }
}

// ---------------- LayerNorm: one wave per 256-wide row, bf16 output ----------------
__global__ __launch_bounds__(256)
void ln_kernel(const float* __restrict__ x, const float* __restrict__ gb,
               unsigned short* __restrict__ y, int rows){
  int gw   = blockIdx.x * 4 + (threadIdx.x >> 6);
  int lane = threadIdx.x & 63;
  if (gw >= rows) return;
  const float* xr = x + (size_t)gw * DMODEL;
  int d0 = lane * 4;
  float4 xv = *(const float4*)(xr + d0);
  float s = xv.x + xv.y + xv.z + xv.w;
  #pragma unroll
  for (int off = 32; off > 0; off >>= 1) s += __shfl_xor(s, off);
  float mu = s * (1.0f / DMODEL);
  float dx0 = xv.x - mu, dx1 = xv.y - mu, dx2 = xv.z - mu, dx3 = xv.w - mu;
  float v = dx0*dx0 + dx1*dx1 + dx2*dx2 + dx3*dx3;
  #pragma unroll
  for (int off = 32; off > 0; off >>= 1) v += __shfl_xor(v, off);
  float rs = rsqrtf(v * (1.0f / DMODEL) + 1e-5f);
  float4 g = *(const float4*)(gb + d0);
  float4 b = *(const float4*)(gb + DMODEL + d0);
  uint2 w;
  w.x = pack_bf16x2(dx0 * rs * g.x + b.x, dx1 * rs * g.y + b.y);
  w.y = pack_bf16x2(dx2 * rs * g.z + b.z, dx3 * rs * g.w + b.w);
  *(uint2*)(y + (size_t)gw * DMODEL + d0) = w;
}

// ---------------- bf16 MFMA GEMM: C[R,N] = A[R,K](bf16) @ W[K,N](fp32->bf16) ----------
// flags: 1=bias, 2=gelu, 4=residual(fp32), 8=bf16 out
// Template MREP = 16x16 fragments per wave in M. Block = 2x2 waves.
// GBM = 32*MREP, GBN = 64, GBK = 32. LDS stride 42 shorts (odd dwords -> bank spread).
#define GBN 64
#define GBK 32
#define GSTR 42
template<int MREP>
__global__ __launch_bounds__(256)
void gemm_mfma(const unsigned short* __restrict__ A, const float* __restrict__ W,
               const float* __restrict__ bias, const float* __restrict__ res,
               void* __restrict__ C, int R, int K, int N, int flags){
  const int GBM = 32 * MREP;
  __shared__ unsigned short Als[2][32 * MREP * GSTR];
  __shared__ unsigned short Bls[2][GBN * GSTR];
  int tid = threadIdx.x;
  int wave = tid >> 6, lane = tid & 63;
  int wm = wave >> 1, wn = wave & 1;
  int l16 = lane & 15, grp = lane >> 4;
  int r0 = blockIdx.y * GBM, c0 = blockIdx.x * GBN;

  int arow = tid >> 2, akc = (tid & 3) * 8;   // 64 rows x 32k per pass
  int bk = tid >> 4, bn4 = (tid & 15) * 4;

  const unsigned short* Ag = A + (size_t)r0 * K;
  const float* Wg = W + c0;
  int ntiles = K / GBK;

  uint4 areg[MREP / 2];
  float4 w0, w1;
  #pragma unroll
  for (int h = 0; h < MREP / 2; h++)
    areg[h] = *(const uint4*)(Ag + (size_t)(arow + h * 64) * K + akc);
  w0 = *(const float4*)(Wg + (size_t)bk * N + bn4);
  w1 = *(const float4*)(Wg + (size_t)(bk + 16) * N + bn4);

  #pragma unroll
  for (int h = 0; h < MREP / 2; h++)
    *(uint4*)&Als[0][(arow + h * 64) * GSTR + akc] = areg[h];
  {
    float wv0[4] = {w0.x, w0.y, w0.z, w0.w};
    float wv1[4] = {w1.x, w1.y, w1.z, w1.w};
    #pragma unroll
    for (int j = 0; j < 4; j++){
      Bls[0][(bn4 + j) * GSTR + bk]      = (unsigned short)bf16_rne(wv0[j]);
      Bls[0][(bn4 + j) * GSTR + bk + 16] = (unsigned short)bf16_rne(wv1[j]);
    }
  }

  f32x4 acc[MREP][2];
  #pragma unroll
  for (int m = 0; m < MREP; m++)
    #pragma unroll
    for (int n = 0; n < 2; n++) acc[m][n] = (f32x4){0.f, 0.f, 0.f, 0.f};

  for (int kt = 0; kt < ntiles; kt++){
    int b = kt & 1;
    __syncthreads();
    if (kt + 1 < ntiles){
      int k0 = (kt + 1) * GBK;
      #pragma unroll
      for (int h = 0; h < MREP / 2; h++)
        areg[h] = *(const uint4*)(Ag + (size_t)(arow + h * 64) * K + k0 + akc);
      w0 = *(const float4*)(Wg + (size_t)(k0 + bk) * N + bn4);
      w1 = *(const float4*)(Wg + (size_t)(k0 + bk + 16) * N + bn4);
    }

    short8 af[MREP], bf[2];
    #pragma unroll
    for (int m = 0; m < MREP; m++)
      af[m] = *(const short8*)&Als[b][(wm * 16 * MREP + m * 16 + l16) * GSTR + grp * 8];
    #pragma unroll
    for (int n = 0; n < 2; n++)
      bf[n] = *(const short8*)&Bls[b][(wn * 32 + n * 16 + l16) * GSTR + grp * 8];
    #pragma unroll
    for (int m = 0; m < MREP; m++)
      #pragma unroll
      for (int n = 0; n < 2; n++)
        acc[m][n] = __builtin_amdgcn_mfma_f32_16x16x32_bf16(af[m], bf[n], acc[m][n], 0, 0, 0);

    if (kt + 1 < ntiles){
      #pragma unroll
      for (int h = 0; h < MREP / 2; h++)
        *(uint4*)&Als[b ^ 1][(arow + h * 64) * GSTR + akc] = areg[h];
      float wv0[4] = {w0.x, w0.y, w0.z, w0.w};
      float wv1[4] = {w1.x, w1.y, w1.z, w1.w};
      #pragma unroll
      for (int j = 0; j < 4; j++){
        Bls[b ^ 1][(bn4 + j) * GSTR + bk]      = (unsigned short)bf16_rne(wv0[j]);
        Bls[b ^ 1][(bn4 + j) * GSTR + bk + 16] = (unsigned short)bf16_rne(wv1[j]);
      }
    }
  }

  #pragma unroll
  for (int n = 0; n < 2; n++){
    int gc = c0 + wn * 32 + n * 16 + l16;
    float bv = (flags & 1) ? bias[gc] : 0.f;
    #pragma unroll
    for (int m = 0; m < MREP; m++){
      int grb = r0 + wm * 16 * MREP + m * 16 + grp * 4;
      #pragma unroll
      for (int r = 0; r < 4; r++){
        float v = acc[m][n][r] + bv;
        if (flags & 2) v = gelu_f(v);
        if (flags & 4) v += res[(size_t)(grb + r) * N + gc];
        if (flags & 8) ((unsigned short*)C)[(size_t)(grb + r) * N + gc] = (unsigned short)bf16_rne(v);
        else           ((float*)C)[(size_t)(grb + r) * N + gc] = v;
      }
    }
  }
}

// ---------------- self-attention: bf16 MFMA flash (swapped-operand layout) ----------
// Q pre-scaled by scale*log2e -> softmax runs in exp2 domain.
// LDS strides: K 42, V 70, P 68 (odd-dword strides -> conflict-free writes).
#define KSTR 42
#define VSTR 70
#define PSTR 68
__global__ __launch_bounds__(256)
void sa_attn_mfma(const unsigned short* __restrict__ qkv, unsigned short* __restrict__ ob){
  int m = blockIdx.z, h = blockIdx.y;
  int tid  = threadIdx.x;
  int wave = tid >> 6, lane = tid & 63;
  int qr = lane & 15, grp = lane >> 4;
  int q0 = blockIdx.x * 64 + wave * 16;

  __shared__ unsigned short Kls[2][64 * KSTR];
  __shared__ unsigned short Vls[2][32 * VSTR];
  __shared__ unsigned short Pls[4][16 * PSTR];
  unsigned short* Pw = Pls[wave];

  const float sl2e = 0.17677669529663687f * 1.4426950408889634f;  // scale * log2(e)

  // Q B-frag, pre-scaled into exp2 domain (unpack-mul-repack once)
  short8 qf;
  {
    short8 qraw = *(const short8*)(qkv + ((size_t)(m * NCTX + q0 + qr)) * 768 + h * 32 + grp * 8);
    #pragma unroll
    for (int i = 0; i < 8; i++){
      float f = __uint_as_float(((unsigned int)(unsigned short)qraw[i]) << 16);
      qf[i] = (short)bf16_rne(f * sl2e);
    }
  }

  int skey = tid >> 2;
  int scol = (tid & 3) * 8;
  const unsigned short* kbase = qkv + (size_t)m * NCTX * 768 + 256 + h * 32 + scol;

  uint4 kreg = *(const uint4*)(kbase + (size_t)skey * 768);
  uint4 vreg = *(const uint4*)(kbase + (size_t)skey * 768 + 256);

  float mq = -1e30f, lq = 0.0f;
  f32x4 acc0 = {0.f, 0.f, 0.f, 0.f};
  f32x4 acc1 = {0.f, 0.f, 0.f, 0.f};

  {
    *(uint4*)&Kls[0][skey * KSTR + scol] = kreg;
    unsigned int vv[4] = {vreg.x, vreg.y, vreg.z, vreg.w};
    #pragma unroll
    for (int j = 0; j < 4; j++){
      Vls[0][(scol + 2 * j    ) * VSTR + skey] = (unsigned short)(vv[j] & 0xffffu);
      Vls[0][(scol + 2 * j + 1) * VSTR + skey] = (unsigned short)(vv[j] >> 16);
    }
  }

  for (int kt = 0; kt < NCTX / 64; kt++){
    int b = kt & 1;
    __syncthreads();
    if (kt + 1 < NCTX / 64){
      kreg = *(const uint4*)(kbase + (size_t)((kt + 1) * 64 + skey) * 768);
      vreg = *(const uint4*)(kbase + (size_t)((kt + 1) * 64 + skey) * 768 + 256);
    }

    f32x4 s0 = {0.f,0.f,0.f,0.f}, s1 = {0.f,0.f,0.f,0.f};
    f32x4 s2 = {0.f,0.f,0.f,0.f}, s3 = {0.f,0.f,0.f,0.f};
    {
      const short8 k0 = *(const short8*)&Kls[b][( 0 + qr) * KSTR + grp * 8];
      const short8 k1 = *(const short8*)&Kls[b][(16 + qr) * KSTR + grp * 8];
      const short8 k2 = *(const short8*)&Kls[b][(32 + qr) * KSTR + grp * 8];
      const short8 k3 = *(const short8*)&Kls[b][(48 + qr) * KSTR + grp * 8];
      s0 = __builtin_amdgcn_mfma_f32_16x16x32_bf16(k0, qf, s0, 0, 0, 0);
      s1 = __builtin_amdgcn_mfma_f32_16x16x32_bf16(k1, qf, s1, 0, 0, 0);
      s2 = __builtin_amdgcn_mfma_f32_16x16x32_bf16(k2, qf, s2, 0, 0, 0);
      s3 = __builtin_amdgcn_mfma_f32_16x16x32_bf16(k3, qf, s3, 0, 0, 0);
    }

    float sc[4][4];
    #pragma unroll
    for (int r = 0; r < 4; r++){
      sc[0][r] = s0[r]; sc[1][r] = s1[r]; sc[2][r] = s2[r]; sc[3][r] = s3[r];
    }
    float tm = sc[0][0];
    #pragma unroll
    for (int kb = 0; kb < 4; kb++)
      #pragma unroll
      for (int r = 0; r < 4; r++) tm = fmaxf(tm, sc[kb][r]);
    tm = fmaxf(tm, __shfl_xor(tm, 16));
    tm = fmaxf(tm, __shfl_xor(tm, 32));

    // defer-rescale: skip (exact) when running max doesn't grow anywhere in the wave
    if (__any(tm > mq)){
      float mn = fmaxf(mq, tm);
      float corr = EXP2(mq - mn);
      lq *= corr;
      #pragma unroll
      for (int r = 0; r < 4; r++){ acc0[r] *= corr; acc1[r] *= corr; }
      mq = mn;
    }

    float ts = 0.f;
    float p[4][4];
    #pragma unroll
    for (int kb = 0; kb < 4; kb++)
      #pragma unroll
      for (int r = 0; r < 4; r++){
        float pv = EXP2(sc[kb][r] - mq);
        p[kb][r] = pv; ts += pv;
      }
    ts += __shfl_xor(ts, 16);
    ts += __shfl_xor(ts, 32);
    lq += ts;

    #pragma unroll
    for (int kb = 0; kb < 4; kb++){
      *(unsigned int*)&Pw[qr * PSTR + kb * 16 + grp * 4]     = pack_bf16x2_trunc(p[kb][0], p[kb][1]);
      *(unsigned int*)&Pw[qr * PSTR + kb * 16 + grp * 4 + 2] = pack_bf16x2_trunc(p[kb][2], p[kb][3]);
    }

    #pragma unroll
    for (int hh = 0; hh < 2; hh++){
      const short8 pf = *(const short8*)&Pw[qr * PSTR + hh * 32 + grp * 8];
      const short8 v0 = *(const short8*)&Vls[b][( 0 + qr) * VSTR + hh * 32 + grp * 8];
      const short8 v1 = *(const short8*)&Vls[b][(16 + qr) * VSTR + hh * 32 + grp * 8];
      acc0 = __builtin_amdgcn_mfma_f32_16x16x32_bf16(v0, pf, acc0, 0, 0, 0);
      acc1 = __builtin_amdgcn_mfma_f32_16x16x32_bf16(v1, pf, acc1, 0, 0, 0);
    }

    if (kt + 1 < NCTX / 64){
      *(uint4*)&Kls[b ^ 1][skey * KSTR + scol] = kreg;
      unsigned int vv[4] = {vreg.x, vreg.y, vreg.z, vreg.w};
      #pragma unroll
      for (int j = 0; j < 4; j++){
        Vls[b ^ 1][(scol + 2 * j    ) * VSTR + skey] = (unsigned short)(vv[j] & 0xffffu);
        Vls[b ^ 1][(scol + 2 * j + 1) * VSTR + skey] = (unsigned short)(vv[j] >> 16);
      }
    }
  }

  float inv = 1.0f / lq;
  unsigned short* op = ob + ((size_t)(m * NCTX + q0 + qr)) * DMODEL + h * DHEAD;
  uint2 o16a, o16b;
  o16a.x = pack_bf16x2(acc0[0] * inv, acc0[1] * inv);
  o16a.y = pack_bf16x2(acc0[2] * inv, acc0[3] * inv);
  o16b.x = pack_bf16x2(acc1[0] * inv, acc1[1] * inv);
  o16b.y = pack_bf16x2(acc1[2] * inv, acc1[3] * inv);
  *(uint2*)(op + grp * 4)      = o16a;
  *(uint2*)(op + 16 + grp * 4) = o16b;
}

// ---------------- cross-attention over 9 gathered neighbours (bf16 out) -----------
__global__ __launch_bounds__(256)
void ca_attn_kernel(const float* __restrict__ qb, const float* __restrict__ kv,
                    const int* __restrict__ idx, const float* __restrict__ mask,
                    unsigned short* __restrict__ ob){
  int g = blockIdx.x;
  int m = g >> 11;
  int tid = threadIdx.x;
  const float scale = 0.17677669529663687f;
  float q = qb[(size_t)g * DMODEL + tid] * scale;
  float s[KNB];
  int rws[KNB];
  #pragma unroll
  for (int k = 0; k < KNB; k++){
    int row = idx[(size_t)g * KNB + k];
    rws[k] = row;
    float p = q * kv[((size_t)(m * NCTX + row)) * 512 + tid];
    #pragma unroll
    for (int off = 16; off > 0; off >>= 1) p += __shfl_xor(p, off, 32);
    s[k] = (mask[(size_t)g * KNB + k] > 0.5f) ? p : -1e30f;
  }
  float sm = s[0];
  #pragma unroll
  for (int k = 1; k < KNB; k++) sm = fmaxf(sm, s[k]);
  float den = 0.f, w[KNB];
  #pragma unroll
  for (int k = 0; k < KNB; k++){ w[k] = __expf(s[k] - sm); den += w[k]; }
  float inv = 1.0f / den;
  float o = 0.f;
  #pragma unroll
  for (int k = 0; k < KNB; k++)
    o += w[k] * kv[((size_t)(m * NCTX + rws[k])) * 512 + 256 + tid];
  ob[(size_t)g * DMODEL + tid] = (unsigned short)bf16_rne(o * inv);
}

// ---------------- host launch helper ----------------
static inline void launch_gemm(const unsigned short* A, const float* W, const float* bias,
                               const float* res, void* C, int R, int K, int N, int flags,
                               hipStream_t stream){
  if (N == 256)
    gemm_mfma<2><<<dim3(N / GBN, R / 64), 256, 0, stream>>>(A, W, bias, res, C, R, K, N, flags);
  else
    gemm_mfma<4><<<dim3(N / GBN, R / 128), 256, 0, stream>>>(A, W, bias, res, C, R, K, N, flags);
}

// ---------------- host launcher ----------------
extern "C" void kernel_launch(void* const* d_in, const int* in_sizes, int n_in,
                              void* d_out, int out_size, void* d_ws, size_t ws_size,
                              hipStream_t stream){
  const float* xc      = (const float*)d_in[0];
  const float* zc_in   = (const float*)d_in[1];
  const float* xt      = (const float*)d_in[2];
  const float* zt_in   = (const float*)d_in[3];
  const float* sa_wqkv = (const float*)d_in[4];
  const float* sa_wo   = (const float*)d_in[5];
  const float* sa_ln1  = (const float*)d_in[6];
  const float* sa_ln2  = (const float*)d_in[7];
  const float* sa_w1   = (const float*)d_in[8];
  const float* sa_b1   = (const float*)d_in[9];
  const float* sa_w2   = (const float*)d_in[10];
  const float* sa_b2   = (const float*)d_in[11];
  const float* ca_wq   = (const float*)d_in[12];
  const float* ca_wkv  = (const float*)d_in[13];
  const float* ca_wo   = (const float*)d_in[14];
  const float* ca_lnq  = (const float*)d_in[15];
  const float* ca_lnkv = (const float*)d_in[16];
  const float* ca_ln2  = (const float*)d_in[17];
  const float* ca_w1   = (const float*)d_in[18];
  const float* ca_b1   = (const float*)d_in[19];
  const float* ca_w2   = (const float*)d_in[20];
  const float* ca_b2   = (const float*)d_in[21];

  if (ws_size < (size_t)WS_FLOATS * sizeof(float)) return;
  float* ws    = (float*)d_ws;
  float* zc    = ws + ZC_OFF;
  unsigned short* hb16 = (unsigned short*)(ws + H_OFF);
  float* qkvb  = ws + QKV_OFF;   // aliased: bf16 qkv / fp32 CA kv / bf16 ffn-mid
  unsigned short* qkv16 = (unsigned short*)qkvb;
  float* qb    = ws + Q_OFF;
  unsigned short* ob16 = (unsigned short*)(ws + O_OFF);
  int*   idxb  = (int*)(ws + IDX_OFF);
  float* maskb = ws + MASK_OFF;
  float* zt    = (float*)d_out;

  copy_kernel<<<RC * DMODEL / 4 / 256, 256, 0, stream>>>(zc_in, zc, RC * DMODEL / 4);
  copy_kernel<<<RT * DMODEL / 4 / 256, 256, 0, stream>>>(zt_in, zt, RT * DMODEL / 4);
  nn_idx_kernel<<<(MB * NTGT) / 256, 256, 0, stream>>>(xc, xt, idxb, maskb);

  for (int l = 0; l < LAYERS; l++){
    // ---------- self-attention block on zc ----------
    ln_kernel<<<RC / 4, 256, 0, stream>>>(zc, sa_ln1 + l * 2 * DMODEL, hb16, RC);
    launch_gemm(hb16, sa_wqkv + (size_t)l * DMODEL * 768, nullptr, nullptr, qkv16,
                RC, DMODEL, 768, 8, stream);
    sa_attn_mfma<<<dim3(NCTX / 64, NHEAD, MB), 256, 0, stream>>>(qkv16, ob16);
    launch_gemm(ob16, sa_wo + (size_t)l * DMODEL * DMODEL, nullptr, zc, zc,
                RC, DMODEL, DMODEL, 4, stream);
    ln_kernel<<<RC / 4, 256, 0, stream>>>(zc, sa_ln2 + l * 2 * DMODEL, hb16, RC);
    launch_gemm(hb16, sa_w1 + (size_t)l * DMODEL * FF, sa_b1 + l * FF, nullptr, qkv16,
                RC, DMODEL, FF, 1 | 2 | 8, stream);
    launch_gemm(qkv16, sa_w2 + (size_t)l * FF * DMODEL, sa_b2 + l * DMODEL, zc, zc,
                RC, FF, DMODEL, 1 | 4, stream);

    // ---------- cross-attention block on zt ----------
    ln_kernel<<<RC / 4, 256, 0, stream>>>(zc, ca_lnkv + l * 2 * DMODEL, hb16, RC);
    launch_gemm(hb16, ca_wkv + (size_t)l * DMODEL * 512, nullptr, nullptr, qkvb,
                RC, DMODEL, 512, 0, stream);
    ln_kernel<<<RT / 4, 256, 0, stream>>>(zt, ca_lnq + l * 2 * DMODEL, hb16, RT);
    launch_gemm(hb16, ca_wq + (size_t)l * DMODEL * DMODEL, nullptr, nullptr, qb,
                RT, DMODEL, DMODEL, 0, stream);
    ca_attn_kernel<<<RT, 256, 0, stream>>>(qb, qkvb, idxb, maskb, ob16);
    launch_gemm(ob16, ca_wo + (size_t)l * DMODEL * DMODEL, nullptr, zt, zt,
                RT, DMODEL, DMODEL, 4, stream);
    ln_kernel<<<RT / 4, 256, 0, stream>>>(zt, ca_ln2 + l * 2 * DMODEL, hb16, RT);
    launch_gemm(hb16, ca_w1 + (size_t)l * DMODEL * FF, ca_b1 + l * FF, nullptr, qkv16,
                RT, DMODEL, FF, 1 | 2 | 8, stream);
    launch_gemm(qkv16, ca_w2 + (size_t)l * FF * DMODEL, ca_b2 + l * DMODEL, zt, zt,
                RT, FF, DMODEL, 1 | 4, stream);
  }
}

// Round 6
// 506.784 us; speedup vs baseline: 1.0181x; 1.0181x over previous
//
#include <hip/hip_runtime.h>
#include <math.h>

// ---------------- problem constants ----------------
#define LAYERS 2
#define DMODEL 256
#define NHEAD  8
#define DHEAD  32
#define FF     512
#define KNB    9
#define MB     4
#define G1D    40
#define G2D    40
#define NTGT   2048
#define NCTX   1600          // G1D*G2D
#define RC     (MB*NCTX)     // 6400 grid rows
#define RT     (MB*NTGT)     // 8192 target rows

typedef __attribute__((ext_vector_type(8))) short short8;   // 8 bf16 (4 VGPRs)
typedef __attribute__((ext_vector_type(4))) float f32x4;    // mfma C/D

#if __has_builtin(__builtin_amdgcn_exp2f)
#define EXP2(x) __builtin_amdgcn_exp2f(x)
#else
#define EXP2(x) exp2f(x)
#endif

// ---------------- workspace layout (float offsets) ----------------
#define ZC_OFF    0
#define H_OFF     1638400
#define QKV_OFF   (H_OFF + 2097152)
// wT (bf16 transposed weights) lives in the tail of the QKV region:
// max live use of QKV region = CA kv fp32 = 3,276,800 floats; wT needs 1,048,576 floats.
#define WT_OFF    (QKV_OFF + 3400000)
#define Q_OFF     (QKV_OFF + 4915200)
#define O_OFF     (Q_OFF + 2097152)
#define IDX_OFF   (O_OFF + 2097152)
#define MASK_OFF  (IDX_OFF + 73728)
#define WS_FLOATS (MASK_OFF + 73728)

// per-layer wT offsets (shorts)
#define WT_LAYER   1048576
#define WT_QKV     0
#define WT_WO      196608
#define WT_W1      262144
#define WT_W2      393216
#define WT_CWQ     524288
#define WT_CWKV    589824
#define WT_CWO     720896
#define WT_CW1     786432
#define WT_CW2     917504

static __device__ __forceinline__ float gelu_f(float x){
  float t = tanhf(0.7978845608028654f * (x + 0.044715f * x * x * x));
  return 0.5f * x * (1.0f + t);
}

static __device__ __forceinline__ unsigned int bf16_rne(float x){
  unsigned int u = __float_as_uint(x);
  return (u + 0x7fffu + ((u >> 16) & 1u)) >> 16;
}
static __device__ __forceinline__ unsigned int pack_bf16x2(float lo, float hi){
  return bf16_rne(lo) | (bf16_rne(hi) << 16);
}
// truncating pack (hot path only: P values in [0,1])
static __device__ __forceinline__ unsigned int pack_bf16x2_trunc(float lo, float hi){
  return (__float_as_uint(lo) >> 16) | (__float_as_uint(hi) & 0xffff0000u);
}

// ---------------- utility: vectorized copy ----------------
__global__ void copy_kernel(const float* __restrict__ src, float* __restrict__ dst, int n4){
  int i = blockIdx.x * blockDim.x + threadIdx.x;
  if (i < n4) ((float4*)dst)[i] = ((const float4*)src)[i];
}

// ---------------- weight prep: fp32 [K][N] -> bf16 [N][K] ----------------
struct TDesc { const float* src; int dstoff; int K; int N; };
struct TTable { TDesc e[18]; };

__global__ __launch_bounds__(256)
void wprep_kernel(TTable t, unsigned short* __restrict__ wt){
  TDesc d = t.e[blockIdx.z];
  int n0 = blockIdx.x * 32, k0 = blockIdx.y * 32;
  if (n0 >= d.N || k0 >= d.K) return;
  __shared__ float tile[32][33];
  int tx = threadIdx.x, ty = threadIdx.y;
  #pragma unroll
  for (int j = 0; j < 4; j++)
    tile[ty * 4 + j][tx] = d.src[(size_t)(k0 + ty * 4 + j) * d.N + n0 + tx];
  __syncthreads();
  #pragma unroll
  for (int j = 0; j < 4; j++)
    wt[(size_t)d.dstoff + (size_t)(n0 + ty * 4 + j) * d.K + k0 + tx] =
        (unsigned short)bf16_rne(tile[tx][ty * 4 + j]);
}

// ---------------- nearest-grid-neighbour index/mask precompute ----------------
__global__ void nn_idx_kernel(const float* __restrict__ xc, const float* __restrict__ xt,
                              int* __restrict__ idx, float* __restrict__ mask){
  int g = blockIdx.x * blockDim.x + threadIdx.x;
  if (g >= MB * NTGT) return;
  int m = g >> 11;
  float x0 = xt[(size_t)g * 2 + 0];
  float x1 = xt[(size_t)g * 2 + 1];
  const float* xcm = xc + (size_t)m * G1D * G2D * 2;
  int n0 = 0; float b0 = 1e30f;
  for (int i = 0; i < G1D; i++){
    float d = fabsf(x0 - xcm[i * (G2D * 2)]);
    if (d < b0){ b0 = d; n0 = i; }
  }
  int n1 = 0; float b1 = 1e30f;
  for (int j = 0; j < G2D; j++){
    float d = fabsf(x1 - xcm[j * 2 + 1]);
    if (d < b1){ b1 = d; n1 = j; }
  }
  #pragma unroll
  for (int a = 0; a < 3; a++){
    int r0 = n0 + a - 1;
    bool v0 = (r0 >= 0) && (r0 < G1D);
    int i0 = min(max(r0, 0), G1D - 1);
    #pragma unroll
    for (int b = 0; b < 3; b++){
      int r1 = n1 + b - 1;
      bool v1 = (r1 >= 0) && (r1 < G2D);
      int i1 = min(max(r1, 0), G2D - 1);
      idx [(size_t)g * KNB + a * 3 + b] = i0 * G2D + i1;
      mask[(size_t)g * KNB + a * 3 + b] = (v0 && v1) ? 1.0f : 0.0f;
    }
  }
}

// ---------------- LayerNorm: one wave per 256-wide row, bf16 output ----------------
__global__ __launch_bounds__(256)
void ln_kernel(const float* __restrict__ x, const float* __restrict__ gb,
               unsigned short* __restrict__ y, int rows){
  int gw   = blockIdx.x * 4 + (threadIdx.x >> 6);
  int lane = threadIdx.x & 63;
  if (gw >= rows) return;
  const float* xr = x + (size_t)gw * DMODEL;
  int d0 = lane * 4;
  float4 xv = *(const float4*)(xr + d0);
  float s = xv.x + xv.y + xv.z + xv.w;
  #pragma unroll
  for (int off = 32; off > 0; off >>= 1) s += __shfl_xor(s, off);
  float mu = s * (1.0f / DMODEL);
  float dx0 = xv.x - mu, dx1 = xv.y - mu, dx2 = xv.z - mu, dx3 = xv.w - mu;
  float v = dx0*dx0 + dx1*dx1 + dx2*dx2 + dx3*dx3;
  #pragma unroll
  for (int off = 32; off > 0; off >>= 1) v += __shfl_xor(v, off);
  float rs = rsqrtf(v * (1.0f / DMODEL) + 1e-5f);
  float4 g = *(const float4*)(gb + d0);
  float4 b = *(const float4*)(gb + DMODEL + d0);
  uint2 w;
  w.x = pack_bf16x2(dx0 * rs * g.x + b.x, dx1 * rs * g.y + b.y);
  w.y = pack_bf16x2(dx2 * rs * g.z + b.z, dx3 * rs * g.w + b.w);
  *(uint2*)(y + (size_t)gw * DMODEL + d0) = w;
}

// ---------------- bf16 MFMA GEMM: C[R,N] = A[R,K](bf16) @ WT[N,K](bf16) -------------
// flags: 1=bias, 2=gelu, 4=residual(fp32), 8=bf16 out
// Template MREP = 16x16 fragments per wave in M. Block = 2x2 waves, GBN=64, GBK=32.
// Both operands row-major [X][K]; identical uint4 reg-staged double-buffered LDS.
#define GBN 64
#define GBK 32
#define GSTR 42
template<int MREP>
__global__ __launch_bounds__(256)
void gemm_mfma(const unsigned short* __restrict__ A, const unsigned short* __restrict__ Wt,
               const float* __restrict__ bias, const float* __restrict__ res,
               void* __restrict__ C, int R, int K, int N, int flags){
  const int GBM = 32 * MREP;
  __shared__ unsigned short Als[2][32 * MREP * GSTR];
  __shared__ unsigned short Bls[2][GBN * GSTR];
  int tid = threadIdx.x;
  int wave = tid >> 6, lane = tid & 63;
  int wm = wave >> 1, wn = wave & 1;
  int l16 = lane & 15, grp = lane >> 4;
  int r0 = blockIdx.y * GBM, c0 = blockIdx.x * GBN;

  int srow = tid >> 2, skc = (tid & 3) * 8;   // 64 rows x 32 k per pass

  const unsigned short* Ag = A + (size_t)r0 * K;
  const unsigned short* Bg = Wt + (size_t)c0 * K;
  int ntiles = K / GBK;

  uint4 areg[MREP / 2], breg;
  #pragma unroll
  for (int h = 0; h < MREP / 2; h++)
    areg[h] = *(const uint4*)(Ag + (size_t)(srow + h * 64) * K + skc);
  breg = *(const uint4*)(Bg + (size_t)srow * K + skc);

  #pragma unroll
  for (int h = 0; h < MREP / 2; h++)
    *(uint4*)&Als[0][(srow + h * 64) * GSTR + skc] = areg[h];
  *(uint4*)&Bls[0][srow * GSTR + skc] = breg;

  f32x4 acc[MREP][2];
  #pragma unroll
  for (int m = 0; m < MREP; m++)
    #pragma unroll
    for (int n = 0; n < 2; n++) acc[m][n] = (f32x4){0.f, 0.f, 0.f, 0.f};

  for (int kt = 0; kt < ntiles; kt++){
    int b = kt & 1;
    __syncthreads();
    if (kt + 1 < ntiles){
      int k0 = (kt + 1) * GBK;
      #pragma unroll
      for (int h = 0; h < MREP / 2; h++)
        areg[h] = *(const uint4*)(Ag + (size_t)(srow + h * 64) * K + k0 + skc);
      breg = *(const uint4*)(Bg + (size_t)srow * K + k0 + skc);
    }

    short8 af[MREP], bf[2];
    #pragma unroll
    for (int m = 0; m < MREP; m++)
      af[m] = *(const short8*)&Als[b][(wm * 16 * MREP + m * 16 + l16) * GSTR + grp * 8];
    #pragma unroll
    for (int n = 0; n < 2; n++)
      bf[n] = *(const short8*)&Bls[b][(wn * 32 + n * 16 + l16) * GSTR + grp * 8];
    #pragma unroll
    for (int m = 0; m < MREP; m++)
      #pragma unroll
      for (int n = 0; n < 2; n++)
        acc[m][n] = __builtin_amdgcn_mfma_f32_16x16x32_bf16(af[m], bf[n], acc[m][n], 0, 0, 0);

    if (kt + 1 < ntiles){
      #pragma unroll
      for (int h = 0; h < MREP / 2; h++)
        *(uint4*)&Als[b ^ 1][(srow + h * 64) * GSTR + skc] = areg[h];
      *(uint4*)&Bls[b ^ 1][srow * GSTR + skc] = breg;
    }
  }

  #pragma unroll
  for (int n = 0; n < 2; n++){
    int gc = c0 + wn * 32 + n * 16 + l16;
    float bv = (flags & 1) ? bias[gc] : 0.f;
    #pragma unroll
    for (int m = 0; m < MREP; m++){
      int grb = r0 + wm * 16 * MREP + m * 16 + grp * 4;
      #pragma unroll
      for (int r = 0; r < 4; r++){
        float v = acc[m][n][r] + bv;
        if (flags & 2) v = gelu_f(v);
        if (flags & 4) v += res[(size_t)(grb + r) * N + gc];
        if (flags & 8) ((unsigned short*)C)[(size_t)(grb + r) * N + gc] = (unsigned short)bf16_rne(v);
        else           ((float*)C)[(size_t)(grb + r) * N + gc] = v;
      }
    }
  }
}

// ---------------- self-attention: bf16 MFMA flash (swapped-operand layout) ----------
// Q pre-scaled by scale*log2e -> softmax in exp2 domain. Straight-line rescale
// (no wave branch: r5 showed control flow kills the compiler's K-loop pipelining).
// Strides: K 42, V 70, P 70 -> all writes/reads <=2-way (free) by bank arithmetic.
#define KSTR 42
#define VSTR 70
#define PSTR 70
__global__ __launch_bounds__(256)
void sa_attn_mfma(const unsigned short* __restrict__ qkv, unsigned short* __restrict__ ob){
  int m = blockIdx.z, h = blockIdx.y;
  int tid  = threadIdx.x;
  int wave = tid >> 6, lane = tid & 63;
  int qr = lane & 15, grp = lane >> 4;
  int q0 = blockIdx.x * 64 + wave * 16;

  __shared__ unsigned short Kls[2][64 * KSTR];
  __shared__ unsigned short Vls[2][32 * VSTR];
  __shared__ unsigned short Pls[4][16 * PSTR];
  unsigned short* Pw = Pls[wave];

  const float sl2e = 0.17677669529663687f * 1.4426950408889634f;  // scale * log2(e)

  short8 qf;
  {
    short8 qraw = *(const short8*)(qkv + ((size_t)(m * NCTX + q0 + qr)) * 768 + h * 32 + grp * 8);
    #pragma unroll
    for (int i = 0; i < 8; i++){
      float f = __uint_as_float(((unsigned int)(unsigned short)qraw[i]) << 16);
      qf[i] = (short)bf16_rne(f * sl2e);
    }
  }

  int skey = tid >> 2;
  int scol = (tid & 3) * 8;
  const unsigned short* kbase = qkv + (size_t)m * NCTX * 768 + 256 + h * 32 + scol;

  uint4 kreg = *(const uint4*)(kbase + (size_t)skey * 768);
  uint4 vreg = *(const uint4*)(kbase + (size_t)skey * 768 + 256);

  float mq = -1e30f, lq = 0.0f;
  f32x4 acc0 = {0.f, 0.f, 0.f, 0.f};
  f32x4 acc1 = {0.f, 0.f, 0.f, 0.f};

  {
    *(uint4*)&Kls[0][skey * KSTR + scol] = kreg;
    unsigned int vv[4] = {vreg.x, vreg.y, vreg.z, vreg.w};
    #pragma unroll
    for (int j = 0; j < 4; j++){
      Vls[0][(scol + 2 * j    ) * VSTR + skey] = (unsigned short)(vv[j] & 0xffffu);
      Vls[0][(scol + 2 * j + 1) * VSTR + skey] = (unsigned short)(vv[j] >> 16);
    }
  }

  for (int kt = 0; kt < NCTX / 64; kt++){
    int b = kt & 1;
    __syncthreads();
    if (kt + 1 < NCTX / 64){
      kreg = *(const uint4*)(kbase + (size_t)((kt + 1) * 64 + skey) * 768);
      vreg = *(const uint4*)(kbase + (size_t)((kt + 1) * 64 + skey) * 768 + 256);
    }

    f32x4 s0 = {0.f,0.f,0.f,0.f}, s1 = {0.f,0.f,0.f,0.f};
    f32x4 s2 = {0.f,0.f,0.f,0.f}, s3 = {0.f,0.f,0.f,0.f};
    {
      const short8 k0 = *(const short8*)&Kls[b][( 0 + qr) * KSTR + grp * 8];
      const short8 k1 = *(const short8*)&Kls[b][(16 + qr) * KSTR + grp * 8];
      const short8 k2 = *(const short8*)&Kls[b][(32 + qr) * KSTR + grp * 8];
      const short8 k3 = *(const short8*)&Kls[b][(48 + qr) * KSTR + grp * 8];
      s0 = __builtin_amdgcn_mfma_f32_16x16x32_bf16(k0, qf, s0, 0, 0, 0);
      s1 = __builtin_amdgcn_mfma_f32_16x16x32_bf16(k1, qf, s1, 0, 0, 0);
      s2 = __builtin_amdgcn_mfma_f32_16x16x32_bf16(k2, qf, s2, 0, 0, 0);
      s3 = __builtin_amdgcn_mfma_f32_16x16x32_bf16(k3, qf, s3, 0, 0, 0);
    }

    float sc[4][4];
    #pragma unroll
    for (int r = 0; r < 4; r++){
      sc[0][r] = s0[r]; sc[1][r] = s1[r]; sc[2][r] = s2[r]; sc[3][r] = s3[r];
    }
    float tm = sc[0][0];
    #pragma unroll
    for (int kb = 0; kb < 4; kb++)
      #pragma unroll
      for (int r = 0; r < 4; r++) tm = fmaxf(tm, sc[kb][r]);
    tm = fmaxf(tm, __shfl_xor(tm, 16));
    tm = fmaxf(tm, __shfl_xor(tm, 32));

    float mn = fmaxf(mq, tm);
    float corr = EXP2(mq - mn);
    lq *= corr;
    #pragma unroll
    for (int r = 0; r < 4; r++){ acc0[r] *= corr; acc1[r] *= corr; }
    mq = mn;

    float ts = 0.f;
    float p[4][4];
    #pragma unroll
    for (int kb = 0; kb < 4; kb++)
      #pragma unroll
      for (int r = 0; r < 4; r++){
        float pv = EXP2(sc[kb][r] - mq);
        p[kb][r] = pv; ts += pv;
      }
    ts += __shfl_xor(ts, 16);
    ts += __shfl_xor(ts, 32);
    lq += ts;

    #pragma unroll
    for (int kb = 0; kb < 4; kb++){
      *(unsigned int*)&Pw[qr * PSTR + kb * 16 + grp * 4]     = pack_bf16x2_trunc(p[kb][0], p[kb][1]);
      *(unsigned int*)&Pw[qr * PSTR + kb * 16 + grp * 4 + 2] = pack_bf16x2_trunc(p[kb][2], p[kb][3]);
    }

    #pragma unroll
    for (int hh = 0; hh < 2; hh++){
      const short8 pf = *(const short8*)&Pw[qr * PSTR + hh * 32 + grp * 8];
      const short8 v0 = *(const short8*)&Vls[b][( 0 + qr) * VSTR + hh * 32 + grp * 8];
      const short8 v1 = *(const short8*)&Vls[b][(16 + qr) * VSTR + hh * 32 + grp * 8];
      acc0 = __builtin_amdgcn_mfma_f32_16x16x32_bf16(v0, pf, acc0, 0, 0, 0);
      acc1 = __builtin_amdgcn_mfma_f32_16x16x32_bf16(v1, pf, acc1, 0, 0, 0);
    }

    if (kt + 1 < NCTX / 64){
      *(uint4*)&Kls[b ^ 1][skey * KSTR + scol] = kreg;
      unsigned int vv[4] = {vreg.x, vreg.y, vreg.z, vreg.w};
      #pragma unroll
      for (int j = 0; j < 4; j++){
        Vls[b ^ 1][(scol + 2 * j    ) * VSTR + skey] = (unsigned short)(vv[j] & 0xffffu);
        Vls[b ^ 1][(scol + 2 * j + 1) * VSTR + skey] = (unsigned short)(vv[j] >> 16);
      }
    }
  }

  float inv = 1.0f / lq;
  unsigned short* op = ob + ((size_t)(m * NCTX + q0 + qr)) * DMODEL + h * DHEAD;
  uint2 o16a, o16b;
  o16a.x = pack_bf16x2(acc0[0] * inv, acc0[1] * inv);
  o16a.y = pack_bf16x2(acc0[2] * inv, acc0[3] * inv);
  o16b.x = pack_bf16x2(acc1[0] * inv, acc1[1] * inv);
  o16b.y = pack_bf16x2(acc1[2] * inv, acc1[3] * inv);
  *(uint2*)(op + grp * 4)      = o16a;
  *(uint2*)(op + 16 + grp * 4) = o16b;
}

// ---------------- cross-attention over 9 gathered neighbours (bf16 out) -----------
__global__ __launch_bounds__(256)
void ca_attn_kernel(const float* __restrict__ qb, const float* __restrict__ kv,
                    const int* __restrict__ idx, const float* __restrict__ mask,
                    unsigned short* __restrict__ ob){
  int g = blockIdx.x;
  int m = g >> 11;
  int tid = threadIdx.x;
  const float scale = 0.17677669529663687f;
  float q = qb[(size_t)g * DMODEL + tid] * scale;
  float s[KNB];
  int rws[KNB];
  #pragma unroll
  for (int k = 0; k < KNB; k++){
    int row = idx[(size_t)g * KNB + k];
    rws[k] = row;
    float p = q * kv[((size_t)(m * NCTX + row)) * 512 + tid];
    #pragma unroll
    for (int off = 16; off > 0; off >>= 1) p += __shfl_xor(p, off, 32);
    s[k] = (mask[(size_t)g * KNB + k] > 0.5f) ? p : -1e30f;
  }
  float sm = s[0];
  #pragma unroll
  for (int k = 1; k < KNB; k++) sm = fmaxf(sm, s[k]);
  float den = 0.f, w[KNB];
  #pragma unroll
  for (int k = 0; k < KNB; k++){ w[k] = __expf(s[k] - sm); den += w[k]; }
  float inv = 1.0f / den;
  float o = 0.f;
  #pragma unroll
  for (int k = 0; k < KNB; k++)
    o += w[k] * kv[((size_t)(m * NCTX + rws[k])) * 512 + 256 + tid];
  ob[(size_t)g * DMODEL + tid] = (unsigned short)bf16_rne(o * inv);
}

// ---------------- host launch helper ----------------
static inline void launch_gemm(const unsigned short* A, const unsigned short* Wt,
                               const float* bias, const float* res, void* C,
                               int R, int K, int N, int flags, hipStream_t stream){
  if (N == 256)
    gemm_mfma<2><<<dim3(N / GBN, R / 64), 256, 0, stream>>>(A, Wt, bias, res, C, R, K, N, flags);
  else
    gemm_mfma<4><<<dim3(N / GBN, R / 128), 256, 0, stream>>>(A, Wt, bias, res, C, R, K, N, flags);
}

// ---------------- host launcher ----------------
extern "C" void kernel_launch(void* const* d_in, const int* in_sizes, int n_in,
                              void* d_out, int out_size, void* d_ws, size_t ws_size,
                              hipStream_t stream){
  const float* xc      = (const float*)d_in[0];
  const float* zc_in   = (const float*)d_in[1];
  const float* xt      = (const float*)d_in[2];
  const float* zt_in   = (const float*)d_in[3];
  const float* sa_wqkv = (const float*)d_in[4];
  const float* sa_wo   = (const float*)d_in[5];
  const float* sa_ln1  = (const float*)d_in[6];
  const float* sa_ln2  = (const float*)d_in[7];
  const float* sa_w1   = (const float*)d_in[8];
  const float* sa_b1   = (const float*)d_in[9];
  const float* sa_w2   = (const float*)d_in[10];
  const float* sa_b2   = (const float*)d_in[11];
  const float* ca_wq   = (const float*)d_in[12];
  const float* ca_wkv  = (const float*)d_in[13];
  const float* ca_wo   = (const float*)d_in[14];
  const float* ca_lnq  = (const float*)d_in[15];
  const float* ca_lnkv = (const float*)d_in[16];
  const float* ca_ln2  = (const float*)d_in[17];
  const float* ca_w1   = (const float*)d_in[18];
  const float* ca_b1   = (const float*)d_in[19];
  const float* ca_w2   = (const float*)d_in[20];
  const float* ca_b2   = (const float*)d_in[21];

  if (ws_size < (size_t)WS_FLOATS * sizeof(float)) return;
  float* ws    = (float*)d_ws;
  float* zc    = ws + ZC_OFF;
  unsigned short* hb16 = (unsigned short*)(ws + H_OFF);
  float* qkvb  = ws + QKV_OFF;   // aliased: bf16 qkv / fp32 CA kv / bf16 ffn-mid
  unsigned short* qkv16 = (unsigned short*)qkvb;
  unsigned short* wt    = (unsigned short*)(ws + WT_OFF);
  float* qb    = ws + Q_OFF;
  unsigned short* ob16 = (unsigned short*)(ws + O_OFF);
  int*   idxb  = (int*)(ws + IDX_OFF);
  float* maskb = ws + MASK_OFF;
  float* zt    = (float*)d_out;

  // ---- weight prep table ----
  TTable tt;
  for (int l = 0; l < LAYERS; l++){
    int b = l * WT_LAYER, i = l * 9;
    tt.e[i + 0] = { sa_wqkv + (size_t)l * 256 * 768, b + WT_QKV,  256, 768 };
    tt.e[i + 1] = { sa_wo   + (size_t)l * 256 * 256, b + WT_WO,   256, 256 };
    tt.e[i + 2] = { sa_w1   + (size_t)l * 256 * 512, b + WT_W1,   256, 512 };
    tt.e[i + 3] = { sa_w2   + (size_t)l * 512 * 256, b + WT_W2,   512, 256 };
    tt.e[i + 4] = { ca_wq   + (size_t)l * 256 * 256, b + WT_CWQ,  256, 256 };
    tt.e[i + 5] = { ca_wkv  + (size_t)l * 256 * 512, b + WT_CWKV, 256, 512 };
    tt.e[i + 6] = { ca_wo   + (size_t)l * 256 * 256, b + WT_CWO,  256, 256 };
    tt.e[i + 7] = { ca_w1   + (size_t)l * 256 * 512, b + WT_CW1,  256, 512 };
    tt.e[i + 8] = { ca_w2   + (size_t)l * 512 * 256, b + WT_CW2,  512, 256 };
  }
  wprep_kernel<<<dim3(24, 16, 18), dim3(32, 8), 0, stream>>>(tt, wt);

  copy_kernel<<<RC * DMODEL / 4 / 256, 256, 0, stream>>>(zc_in, zc, RC * DMODEL / 4);
  copy_kernel<<<RT * DMODEL / 4 / 256, 256, 0, stream>>>(zt_in, zt, RT * DMODEL / 4);
  nn_idx_kernel<<<(MB * NTGT) / 256, 256, 0, stream>>>(xc, xt, idxb, maskb);

  for (int l = 0; l < LAYERS; l++){
    const unsigned short* wl = wt + (size_t)l * WT_LAYER;
    // ---------- self-attention block on zc ----------
    ln_kernel<<<RC / 4, 256, 0, stream>>>(zc, sa_ln1 + l * 2 * DMODEL, hb16, RC);
    launch_gemm(hb16, wl + WT_QKV, nullptr, nullptr, qkv16, RC, DMODEL, 768, 8, stream);
    sa_attn_mfma<<<dim3(NCTX / 64, NHEAD, MB), 256, 0, stream>>>(qkv16, ob16);
    launch_gemm(ob16, wl + WT_WO, nullptr, zc, zc, RC, DMODEL, DMODEL, 4, stream);
    ln_kernel<<<RC / 4, 256, 0, stream>>>(zc, sa_ln2 + l * 2 * DMODEL, hb16, RC);
    launch_gemm(hb16, wl + WT_W1, sa_b1 + l * FF, nullptr, qkv16, RC, DMODEL, FF, 1 | 2 | 8, stream);
    launch_gemm(qkv16, wl + WT_W2, sa_b2 + l * DMODEL, zc, zc, RC, FF, DMODEL, 1 | 4, stream);

    // ---------- cross-attention block on zt ----------
    ln_kernel<<<RC / 4, 256, 0, stream>>>(zc, ca_lnkv + l * 2 * DMODEL, hb16, RC);
    launch_gemm(hb16, wl + WT_CWKV, nullptr, nullptr, qkvb, RC, DMODEL, 512, 0, stream);
    ln_kernel<<<RT / 4, 256, 0, stream>>>(zt, ca_lnq + l * 2 * DMODEL, hb16, RT);
    launch_gemm(hb16, wl + WT_CWQ, nullptr, nullptr, qb, RT, DMODEL, DMODEL, 0, stream);
    ca_attn_kernel<<<RT, 256, 0, stream>>>(qb, qkvb, idxb, maskb, ob16);
    launch_gemm(ob16, wl + WT_CWO, nullptr, zt, zt, RT, DMODEL, DMODEL, 4, stream);
    ln_kernel<<<RT / 4, 256, 0, stream>>>(zt, ca_ln2 + l * 2 * DMODEL, hb16, RT);
    launch_gemm(hb16, wl + WT_CW1, ca_b1 + l * FF, nullptr, qkv16, RT, DMODEL, FF, 1 | 2 | 8, stream);
    launch_gemm(qkv16, wl + WT_CW2, ca_b2 + l * DMODEL, zt, zt, RT, FF, DMODEL, 1 | 4, stream);
  }
}